// Round 16
// baseline (300.434 us; speedup 1.0000x reference)
//
#include <hip/hip_runtime.h>
#include <hip/hip_bf16.h>

#define B_   16
#define T_   2048
#define E_   1024
#define S_   2000
#define HID_ 150
#define GI_  3072

typedef __attribute__((ext_vector_type(8))) short short8;   // 8 bf16 (4 VGPRs)
typedef __attribute__((ext_vector_type(4))) float f32x4;

constexpr int NPAD  = 160;   // HID padded to 10 MFMA col-tiles
constexpr int LSTR  = 168;   // hl row stride (bf16): 336 B
constexpr int MROWS = 64;    // rows per MLP block

__device__ __forceinline__ void gload16(const void* gsrc, void* ldst) {
    __builtin_amdgcn_global_load_lds(
        (const __attribute__((address_space(1))) unsigned int*)gsrc,
        (__attribute__((address_space(3))) unsigned int*)ldst,
        16, 0, 0);   // 16B/lane, wave-uniform LDS base + lane*16
}

__device__ __forceinline__ short8 pack8(float4 a, float4 b) {
    union { __hip_bfloat162 h[4]; short8 s; } u;
    u.h[0] = __float22bfloat162_rn(make_float2(a.x, a.y));
    u.h[1] = __float22bfloat162_rn(make_float2(a.z, a.w));
    u.h[2] = __float22bfloat162_rn(make_float2(b.x, b.y));
    u.h[3] = __float22bfloat162_rn(make_float2(b.z, b.w));
    return u.s;
}

__device__ __forceinline__ short8 pack8v(f32x4 a, f32x4 b) {
    union { __hip_bfloat162 h[4]; short8 s; } u;
    u.h[0] = __float22bfloat162_rn(make_float2(a.x, a.y));
    u.h[1] = __float22bfloat162_rn(make_float2(a.z, a.w));
    u.h[2] = __float22bfloat162_rn(make_float2(b.x, b.y));
    u.h[3] = __float22bfloat162_rn(make_float2(b.z, b.w));
    return u.s;
}

// Weight transposes (f32 [K][150] -> bf16 [160][K], zero-padded) + ws zero-row.
__global__ __launch_bounds__(256)
void transpose_all(const float* __restrict__ Wa1, const float* __restrict__ Wa2,
                   const float* __restrict__ Ws1, const float* __restrict__ Ws2,
                   __hip_bfloat16* __restrict__ Wt1a, __hip_bfloat16* __restrict__ Wt2a,
                   __hip_bfloat16* __restrict__ Wt1s, __hip_bfloat16* __restrict__ Wt2s,
                   float* __restrict__ zerobuf)
{
    const int s0 = 160 * 1024, s1 = 160 * 160, s2 = 160 * 3072, s3 = 160 * 160;
    int i = blockIdx.x * 256 + threadIdx.x;
    if (i < s0) {
        int n = i >> 10, k = i & 1023;
        Wt1a[i] = __float2bfloat16(n < HID_ ? Wa1[k * HID_ + n] : 0.f);
    } else if (i < s0 + s1) {
        int j = i - s0, n = j / 160, k = j - n * 160;
        Wt2a[j] = __float2bfloat16((n < HID_ && k < HID_) ? Wa2[k * HID_ + n] : 0.f);
    } else if (i < s0 + s1 + s2) {
        int j = i - s0 - s1, n = j / 3072, k = j - n * 3072;
        Wt1s[j] = __float2bfloat16(n < HID_ ? Ws1[k * HID_ + n] : 0.f);
    } else if (i < s0 + s1 + s2 + s3) {
        int j = i - s0 - s1 - s2, n = j / 160, k = j - n * 160;
        Wt2s[j] = __float2bfloat16((n < HID_ && k < HID_) ? Ws2[k * HID_ + n] : 0.f);
    } else if (i < s0 + s1 + s2 + s3 + 1024) {
        zerobuf[i - s0 - s1 - s2 - s3] = 0.f;    // 4 KB zero row
    }
}

// attn MLP: 1024 -> 150 relu -> 150 relu -> 1, 64 rows/block, 4 waves.
// A(f32)+B(bf16) DMA-staged per 64-K chunk, 2-phase dbuf. ~HBM-BW-bound (25us).
template<int K1>
__global__ __launch_bounds__(256, 2)
void mlp_mfma(const float* __restrict__ xin,
              const __hip_bfloat16* __restrict__ Wt1, const float* __restrict__ b1,
              const __hip_bfloat16* __restrict__ Wt2, const float* __restrict__ b2,
              const float* __restrict__ W3, const float* __restrict__ b3,
              float* __restrict__ outp)
{
    constexpr int NC  = K1 / 64;
    constexpr int ACH = 64 * 64 * 4;
    constexpr int BCH = 160 * 64 * 2;
    __shared__ __align__(16) char smem[2 * ACH + 2 * BCH];

    const int tid  = threadIdx.x;
    const int lane = tid & 63;
    const int w    = tid >> 6;
    const int rg   = w >> 1;
    const int cg   = w & 1;
    const int lr   = lane & 15;
    const int hi   = lane >> 4;

    const long long row0 = (long long)blockIdx.x * MROWS;

    auto stageA = [&](int bi, int c) {
        char* dst = smem + bi * ACH;
#pragma unroll
        for (int j = 0; j < 4; ++j) {
            const int row  = (w * 4 + j) * 4 + (lane >> 4);
            const int slot = (lane & 15) ^ (row & 7);
            gload16(xin + (row0 + row) * (long long)K1 + c * 64 + slot * 4,
                    dst + (w * 4 + j) * 1024);
        }
    };
    auto stageB = [&](int bi, int c) {
        char* dst = smem + 2 * ACH + bi * BCH;
#pragma unroll
        for (int j = 0; j < 5; ++j) {
            const int nrow = (w * 5 + j) * 8 + (lane >> 3);
            const int slot = (lane & 7) ^ (nrow & 7);
            gload16(Wt1 + (long long)nrow * K1 + c * 64 + slot * 8,
                    dst + (w * 5 + j) * 1024);
        }
    };

    f32x4 acc[2][5];
#pragma unroll
    for (int rt = 0; rt < 2; ++rt)
#pragma unroll
        for (int nt = 0; nt < 5; ++nt) acc[rt][nt] = (f32x4){0.f, 0.f, 0.f, 0.f};

    stageA(0, 0);
    stageB(0, 0);

    for (int c = 0; c < NC; ++c) {
        __syncthreads();
        if (c + 1 < NC) { stageA((c + 1) & 1, c + 1); stageB((c + 1) & 1, c + 1); }
        const int bi = c & 1;
        const char* sA = smem + bi * ACH;
        const char* sB = smem + 2 * ACH + bi * BCH;
#pragma unroll
        for (int ks = 0; ks < 2; ++ks) {
            short8 bfr[5];
#pragma unroll
            for (int nt = 0; nt < 5; ++nt) {
                const int nrow = cg * 80 + nt * 16 + lr;
                const int slot = (ks * 4 + hi) ^ (nrow & 7);
                bfr[nt] = *(const short8*)(sB + nrow * 128 + slot * 16);
            }
#pragma unroll
            for (int rt = 0; rt < 2; ++rt) {
                const int r = rg * 32 + rt * 16 + lr;
                const int s0i = (ks * 8 + hi * 2) ^ (r & 7);
                const int s1i = (ks * 8 + hi * 2 + 1) ^ (r & 7);
                float4 a0 = *(const float4*)(sA + r * 256 + s0i * 16);
                float4 a1 = *(const float4*)(sA + r * 256 + s1i * 16);
                short8 afr = pack8(a0, a1);
#pragma unroll
                for (int nt = 0; nt < 5; ++nt)
                    acc[rt][nt] = __builtin_amdgcn_mfma_f32_16x16x32_bf16(
                        afr, bfr[nt], acc[rt][nt], 0, 0, 0);
            }
        }
    }
    __syncthreads();

    __hip_bfloat16* hl = (__hip_bfloat16*)smem;

#pragma unroll
    for (int nt = 0; nt < 5; ++nt) {
        const int ch = cg * 80 + nt * 16 + lr;
        const float bb = (ch < HID_) ? b1[ch] : 0.f;
#pragma unroll
        for (int rt = 0; rt < 2; ++rt)
#pragma unroll
            for (int r4 = 0; r4 < 4; ++r4) {
                const int row = rg * 32 + rt * 16 + hi * 4 + r4;
                float h = acc[rt][nt][r4] + bb;
                hl[row * LSTR + ch] = __float2bfloat16(h > 0.f ? h : 0.f);
            }
    }
    __syncthreads();

    f32x4 acc2[2][5];
#pragma unroll
    for (int rt = 0; rt < 2; ++rt)
#pragma unroll
        for (int nt = 0; nt < 5; ++nt) acc2[rt][nt] = (f32x4){0.f, 0.f, 0.f, 0.f};

#pragma unroll
    for (int ks = 0; ks < 5; ++ks) {
        const int k0 = ks * 32 + hi * 8;
        short8 bfr[5];
#pragma unroll
        for (int nt = 0; nt < 5; ++nt)
            bfr[nt] = *(const short8*)(Wt2 + (cg * 80 + nt * 16 + lr) * NPAD + k0);
#pragma unroll
        for (int rt = 0; rt < 2; ++rt) {
            short8 afr = *(const short8*)&hl[(rg * 32 + rt * 16 + lr) * LSTR + k0];
#pragma unroll
            for (int nt = 0; nt < 5; ++nt)
                acc2[rt][nt] = __builtin_amdgcn_mfma_f32_16x16x32_bf16(
                    afr, bfr[nt], acc2[rt][nt], 0, 0, 0);
        }
    }
    __syncthreads();

#pragma unroll
    for (int nt = 0; nt < 5; ++nt) {
        const int ch = cg * 80 + nt * 16 + lr;
        const float bb = (ch < HID_) ? b2[ch] : 0.f;
#pragma unroll
        for (int rt = 0; rt < 2; ++rt)
#pragma unroll
            for (int r4 = 0; r4 < 4; ++r4) {
                const int row = rg * 32 + rt * 16 + hi * 4 + r4;
                float h = acc2[rt][nt][r4] + bb;
                hl[row * LSTR + ch] = __float2bfloat16(h > 0.f ? h : 0.f);
            }
    }
    __syncthreads();

    {
        const int row = tid >> 2, quad = tid & 3;
        const int kb = quad * 38;
        const int ke = (kb + 38 > HID_) ? HID_ : kb + 38;
        float s = 0.f;
        for (int k = kb; k < ke; ++k)
            s += __bfloat162float(hl[row * LSTR + k]) * W3[k];
        s += __shfl_xor(s, 1);
        s += __shfl_xor(s, 2);
        if (quad == 0) outp[row0 + row] = s + b3[0];
    }
}

// ---- weighted prefix sum over tokens (reference's cumsum trick) ----
__global__ __launch_bounds__(256)
void wsum_tiles(const float* __restrict__ x, const float* __restrict__ attn,
                float* __restrict__ P)
{
    const int b = blockIdx.x >> 5, tile = blockIdx.x & 31, q = threadIdx.x;
    const float* xb = x + ((long long)b * T_ + tile * 64) * E_ + q * 4;
    const float* ab = attn + b * T_ + tile * 64;
    f32x4 a0 = (f32x4){0.f, 0.f, 0.f, 0.f}, a1 = a0;
#pragma unroll 8
    for (int t = 0; t < 64; t += 2) {
        a0 += ab[t]     * *(const f32x4*)(xb + (long long)t * E_);
        a1 += ab[t + 1] * *(const f32x4*)(xb + (long long)(t + 1) * E_);
    }
    *(f32x4*)(P + ((long long)(b * 32 + tile)) * E_ + q * 4) = a0 + a1;
}

__global__ __launch_bounds__(256)
void wcumsum(const float* __restrict__ x, const float* __restrict__ attn,
             const float* __restrict__ P, float* __restrict__ csum)
{
    const int b = blockIdx.x >> 5, tile = blockIdx.x & 31, q = threadIdx.x;
    f32x4 pfx = (f32x4){0.f, 0.f, 0.f, 0.f};
    for (int tau = 0; tau < tile; ++tau)
        pfx += *(const f32x4*)(P + ((long long)(b * 32 + tau)) * E_ + q * 4);
    const float* xb = x + ((long long)b * T_ + tile * 64) * E_ + q * 4;
    float*       cb = csum + ((long long)b * T_ + tile * 64) * E_ + q * 4;
    const float* ab = attn + b * T_ + tile * 64;
    f32x4 acc = pfx;
#pragma unroll 4
    for (int t = 0; t < 64; ++t) {
        acc += ab[t] * *(const f32x4*)(xb + (long long)t * E_);
        *(f32x4*)(cb + (long long)t * E_) = acc;
    }
}

// Fused span construction + score MLP. 64 spans/block, 512 threads (8 waves).
// Counted-vmcnt barriers (T4): stores stay in flight across phases; per phase
// exactly 6 VMEM ops (4 A-loads + 2 stores) follow the B-DMAs, so vmcnt(6)
// guarantees each wave's own DMAs landed before s_barrier; lgkmcnt(0) covers
// ds_write visibility. Removes the per-phase store-drain stall.
__global__ __launch_bounds__(512, 4)
void span_score(const float* __restrict__ x, const float* __restrict__ csum,
                const float* __restrict__ zrow,
                const int* __restrict__ starts, const int* __restrict__ lengths,
                const int* __restrict__ nspans,
                const __hip_bfloat16* __restrict__ Wt1, const float* __restrict__ b1,
                const __hip_bfloat16* __restrict__ Wt2, const float* __restrict__ b2,
                const float* __restrict__ W3, const float* __restrict__ b3,
                float* __restrict__ spanout, float* __restrict__ scoreout)
{
    // layout: sA dbuf 2x8KB @0 ; sB dbuf 2x20KB @16384 ; meta @57344
    __shared__ __align__(16) char smem[58112];
    int* stL = (int*)(smem + 57344);
    int* enL = (int*)(smem + 57600);
    int* bL  = (int*)(smem + 57856);

    const int tid  = threadIdx.x;
    const int lane = tid & 63;
    const int w    = tid >> 6;     // 0..7
    const int rg   = w >> 1;       // 0..3 : rows rg*16..+16
    const int cg   = w & 1;        // cols cg*80..+80
    const int lr   = lane & 15;
    const int hi   = lane >> 4;

    // bijective XCD-aware swizzle over 500 blocks
    int bid = blockIdx.x;
    {
        const int qq = 500 / 8, rr = 500 % 8;
        const int xcd = bid % 8, i = bid / 8;
        bid = (xcd < rr ? xcd * (qq + 1) : rr * (qq + 1) + (xcd - rr) * qq) + i;
    }
    const int span0 = bid * 64;

    if (tid < 64) {
        const int sp = span0 + tid;
        const int b  = sp / S_;
        const int s  = sp - b * S_;
        const bool val = s < nspans[b];
        const int st = val ? starts[sp] : 0;
        stL[tid] = st;
        enL[tid] = val ? (st + lengths[sp]) : -1;
        bL[tid]  = b;
    }
    __syncthreads();

    const int r    = tid >> 3;     // constructor row 0..63
    const int q    = tid & 7;      // 8 floats per thread
    const int st_r = stL[r];
    const int en_r = enL[r];       // -1 for invalid spans
    const bool valid = en_r >= st_r;
    const long long sp_r = span0 + r;
    const float* xb = x    + (long long)bL[r] * T_ * E_;
    const float* cb = csum + (long long)bL[r] * T_ * E_;

    // precomputed per-thread source rows (zero-row when absent / invalid)
    const float* px_st = valid ? xb + (long long)st_r * E_ : zrow;
    const float* px_en = valid ? xb + (long long)en_r * E_ : zrow;
    const float* pc_en = valid ? cb + (long long)en_r * E_ : zrow;
    const float* pc_st = (valid && st_r > 0) ? cb + (long long)(st_r - 1) * E_ : zrow;

    auto srcs = [&](int c, const float*& s1, const float*& s2) {
        s1 = (c < 16) ? px_st : ((c < 32) ? px_en : pc_en);
        s2 = (c < 32) ? zrow : pc_st;
    };
    auto emit = [&](int bi, int c, f32x4 l0, f32x4 l1, f32x4 l2, f32x4 l3) {
        f32x4 v0 = l0 - l2, v1 = l1 - l3;
        float* orow = spanout + sp_r * (3 * E_) + c * 64 + q * 8;
        *(f32x4*)orow       = v0;
        *(f32x4*)(orow + 4) = v1;
        *(short8*)(smem + bi * 8192 + r * 128 + ((q ^ (r & 7)) * 16)) = pack8v(v0, v1);
    };

    auto stageB = [&](int bi, int c) {
        char* dst = smem + 16384 + bi * 20480;
#pragma unroll
        for (int j = 0; j < 3; ++j) {
            const int idx = w * 3 + j;      // 20 x 1KB pieces over 8 waves
            if (idx < 20) {
                const int nrow = idx * 8 + (lane >> 3);
                const int slot = (lane & 7) ^ (nrow & 7);
                gload16(Wt1 + (long long)nrow * GI_ + c * 64 + slot * 8,
                        dst + idx * 1024);
            }
        }
    };

    // ---------------- stage 1: 3072 -> 160 ----------------
    f32x4 acc[5];
#pragma unroll
    for (int nt = 0; nt < 5; ++nt) acc[nt] = (f32x4){0.f, 0.f, 0.f, 0.f};

    // prologue: B DMA FIRST, then chunk-0 construction (= 6 VMEM after DMAs)
    stageB(0, 0);
    asm volatile("" ::: "memory");
    {
        const float *s1, *s2;
        srcs(0, s1, s2);
        emit(0, 0,
             *(const f32x4*)(s1 + q * 8), *(const f32x4*)(s1 + q * 8 + 4),
             *(const f32x4*)(s2 + q * 8), *(const f32x4*)(s2 + q * 8 + 4));
    }

    for (int c = 0; c < 48; ++c) {
        // counted-vmcnt barrier: own-wave B-DMAs (issued 6 VMEM ops ago) done;
        // spanout stores may remain in flight. lgkmcnt(0): ds ops visible.
        asm volatile("s_waitcnt vmcnt(6) lgkmcnt(0)" ::: "memory");
        __builtin_amdgcn_s_barrier();
        const int bi = c & 1;
        if (c + 1 < 48) stageB(bi ^ 1, c + 1);
        asm volatile("" ::: "memory");   // pin order: DMAs before the 6 VMEM ops
        f32x4 l0, l1, l2, l3;
        if (c + 1 < 48) {
            const float *s1, *s2;
            srcs(c + 1, s1, s2);
            const int off = ((c + 1) & 15) * 64 + q * 8;
            l0 = *(const f32x4*)(s1 + off);
            l1 = *(const f32x4*)(s1 + off + 4);
            l2 = *(const f32x4*)(s2 + off);
            l3 = *(const f32x4*)(s2 + off + 4);
        }
        const char* sAc = smem + bi * 8192;
        const char* sBc = smem + 16384 + bi * 20480;
#pragma unroll
        for (int ks = 0; ks < 2; ++ks) {
            short8 bfr[5];
#pragma unroll
            for (int nt = 0; nt < 5; ++nt) {
                const int nrow = cg * 80 + nt * 16 + lr;
                const int slot = (ks * 4 + hi) ^ (nrow & 7);
                bfr[nt] = *(const short8*)(sBc + nrow * 128 + slot * 16);
            }
            const int r2 = rg * 16 + lr;
            const int sl = (ks * 4 + hi) ^ (r2 & 7);
            short8 afr = *(const short8*)(sAc + r2 * 128 + sl * 16);
#pragma unroll
            for (int nt = 0; nt < 5; ++nt)
                acc[nt] = __builtin_amdgcn_mfma_f32_16x16x32_bf16(
                    afr, bfr[nt], acc[nt], 0, 0, 0);
        }
        if (c + 1 < 48) emit(bi ^ 1, c + 1, l0, l1, l2, l3);
    }
    // stage-1 done: only LDS visibility needed before smem reuse
    asm volatile("s_waitcnt lgkmcnt(0)" ::: "memory");
    __builtin_amdgcn_s_barrier();

    __hip_bfloat16* hl = (__hip_bfloat16*)smem;   // 21.5 KB alias

#pragma unroll
    for (int nt = 0; nt < 5; ++nt) {
        const int ch = cg * 80 + nt * 16 + lr;
        const float bb = (ch < HID_) ? b1[ch] : 0.f;
#pragma unroll
        for (int r4 = 0; r4 < 4; ++r4) {
            const int row = rg * 16 + hi * 4 + r4;
            float h = acc[nt][r4] + bb;
            hl[row * LSTR + ch] = __float2bfloat16(h > 0.f ? h : 0.f);
        }
    }
    __syncthreads();

    // ---------------- stage 2: 160 -> 160 ----------------
    f32x4 acc2[5];
#pragma unroll
    for (int nt = 0; nt < 5; ++nt) acc2[nt] = (f32x4){0.f, 0.f, 0.f, 0.f};

#pragma unroll
    for (int ks = 0; ks < 5; ++ks) {
        const int k0 = ks * 32 + hi * 8;
        short8 bfr[5];
#pragma unroll
        for (int nt = 0; nt < 5; ++nt)
            bfr[nt] = *(const short8*)(Wt2 + (cg * 80 + nt * 16 + lr) * NPAD + k0);
        short8 afr = *(const short8*)&hl[(rg * 16 + lr) * LSTR + k0];
#pragma unroll
        for (int nt = 0; nt < 5; ++nt)
            acc2[nt] = __builtin_amdgcn_mfma_f32_16x16x32_bf16(
                afr, bfr[nt], acc2[nt], 0, 0, 0);
    }
    __syncthreads();

#pragma unroll
    for (int nt = 0; nt < 5; ++nt) {
        const int ch = cg * 80 + nt * 16 + lr;
        const float bb = (ch < HID_) ? b2[ch] : 0.f;
#pragma unroll
        for (int r4 = 0; r4 < 4; ++r4) {
            const int row = rg * 16 + hi * 4 + r4;
            float h = acc2[nt][r4] + bb;
            hl[row * LSTR + ch] = __float2bfloat16(h > 0.f ? h : 0.f);
        }
    }
    __syncthreads();

    // ---------------- stage 3: 150 -> 1 (8 threads/row) ----------------
    {
        const int row = tid >> 3, oct = tid & 7;
        const int kb = oct * 19;
        const int ke = (kb + 19 > HID_) ? HID_ : kb + 19;
        float s = 0.f;
        for (int k = kb; k < ke; ++k)
            s += __bfloat162float(hl[row * LSTR + k]) * W3[k];
        s += __shfl_xor(s, 1);
        s += __shfl_xor(s, 2);
        s += __shfl_xor(s, 4);
        if (oct == 0) scoreout[span0 + row] = s + b3[0];
    }
}

extern "C" void kernel_launch(void* const* d_in, const int* in_sizes, int n_in,
                              void* d_out, int out_size, void* d_ws, size_t ws_size,
                              hipStream_t stream) {
    const float* x       = (const float*)d_in[0];
    const int*   starts  = (const int*)d_in[1];
    const int*   lengths = (const int*)d_in[2];
    const int*   nspans  = (const int*)d_in[3];
    const float* Wa1 = (const float*)d_in[4];
    const float* ba1 = (const float*)d_in[5];
    const float* Wa2 = (const float*)d_in[6];
    const float* ba2 = (const float*)d_in[7];
    const float* Wa3 = (const float*)d_in[8];
    const float* ba3 = (const float*)d_in[9];
    const float* Ws1 = (const float*)d_in[10];
    const float* bs1 = (const float*)d_in[11];
    const float* Ws2 = (const float*)d_in[12];
    const float* bs2 = (const float*)d_in[13];
    const float* Ws3 = (const float*)d_in[14];
    const float* bs3 = (const float*)d_in[15];

    float* out        = (float*)d_out;                       // span_emb [B,S,3E]
    float* out_scores = out + (long long)B_ * S_ * 3 * E_;   // scores [B,S]

    char* ws = (char*)d_ws;
    float*          attn    = (float*)ws;                       // 131072 B
    __hip_bfloat16* Wt1a    = (__hip_bfloat16*)(ws + 131072);   // 160*1024*2
    __hip_bfloat16* Wt2a    = (__hip_bfloat16*)(ws + 458752);   // 160*160*2
    __hip_bfloat16* Wt1s    = (__hip_bfloat16*)(ws + 509952);   // 160*3072*2
    __hip_bfloat16* Wt2s    = (__hip_bfloat16*)(ws + 1492992);  // 160*160*2
    float*          zerobuf = (float*)(ws + 1544192);           // 4 KB zeros
    float*          Ptile   = (float*)(ws + 2097152);           // 2 MB
    float*          csum    = (float*)(ws + 4194304);           // 134 MB

    // 0) weight transposes + zero-row init
    transpose_all<<<2765, 256, 0, stream>>>(Wa1, Wa2, Ws1, Ws2,
                                            Wt1a, Wt2a, Wt1s, Wt2s, zerobuf);

    // 1) attention score per token (32768 rows, 512 blocks)
    mlp_mfma<E_><<<(B_ * T_) / MROWS, 256, 0, stream>>>
        (x, Wt1a, ba1, Wt2a, ba2, Wa3, ba3, attn);

    // 2) weighted prefix sums: tile sums then full csum
    wsum_tiles<<<B_ * 32, 256, 0, stream>>>(x, attn, Ptile);
    wcumsum   <<<B_ * 32, 256, 0, stream>>>(x, attn, Ptile, csum);

    // 3) fused span construction + mention-score MLP (500 blocks)
    span_score<<<500, 512, 0, stream>>>
        (x, csum, zerobuf, starts, lengths, nspans,
         Wt1s, bs1, Wt2s, bs2, Ws3, bs3, out, out_scores);
}

// Round 17
// 264.076 us; speedup vs baseline: 1.1377x; 1.1377x over previous
//
#include <hip/hip_runtime.h>
#include <hip/hip_bf16.h>

#define B_   16
#define T_   2048
#define E_   1024
#define S_   2000
#define HID_ 150
#define GI_  3072

typedef __attribute__((ext_vector_type(8))) short short8;   // 8 bf16 (4 VGPRs)
typedef __attribute__((ext_vector_type(4))) float f32x4;

constexpr int NPAD  = 160;   // HID padded to 10 MFMA col-tiles
constexpr int LSTR  = 168;   // hl row stride (bf16): 336 B
constexpr int MROWS = 64;    // rows per MLP block

__device__ __forceinline__ void gload16(const void* gsrc, void* ldst) {
    __builtin_amdgcn_global_load_lds(
        (const __attribute__((address_space(1))) unsigned int*)gsrc,
        (__attribute__((address_space(3))) unsigned int*)ldst,
        16, 0, 0);   // 16B/lane, wave-uniform LDS base + lane*16
}

__device__ __forceinline__ short8 pack8(float4 a, float4 b) {
    union { __hip_bfloat162 h[4]; short8 s; } u;
    u.h[0] = __float22bfloat162_rn(make_float2(a.x, a.y));
    u.h[1] = __float22bfloat162_rn(make_float2(a.z, a.w));
    u.h[2] = __float22bfloat162_rn(make_float2(b.x, b.y));
    u.h[3] = __float22bfloat162_rn(make_float2(b.z, b.w));
    return u.s;
}

__device__ __forceinline__ short8 pack8v(f32x4 a, f32x4 b) {
    union { __hip_bfloat162 h[4]; short8 s; } u;
    u.h[0] = __float22bfloat162_rn(make_float2(a.x, a.y));
    u.h[1] = __float22bfloat162_rn(make_float2(a.z, a.w));
    u.h[2] = __float22bfloat162_rn(make_float2(b.x, b.y));
    u.h[3] = __float22bfloat162_rn(make_float2(b.z, b.w));
    return u.s;
}

// Weight transposes (f32 [K][150] -> bf16 [160][K], zero-padded) + ws zero-row.
__global__ __launch_bounds__(256)
void transpose_all(const float* __restrict__ Wa1, const float* __restrict__ Wa2,
                   const float* __restrict__ Ws1, const float* __restrict__ Ws2,
                   __hip_bfloat16* __restrict__ Wt1a, __hip_bfloat16* __restrict__ Wt2a,
                   __hip_bfloat16* __restrict__ Wt1s, __hip_bfloat16* __restrict__ Wt2s,
                   float* __restrict__ zerobuf)
{
    const int s0 = 160 * 1024, s1 = 160 * 160, s2 = 160 * 3072, s3 = 160 * 160;
    int i = blockIdx.x * 256 + threadIdx.x;
    if (i < s0) {
        int n = i >> 10, k = i & 1023;
        Wt1a[i] = __float2bfloat16(n < HID_ ? Wa1[k * HID_ + n] : 0.f);
    } else if (i < s0 + s1) {
        int j = i - s0, n = j / 160, k = j - n * 160;
        Wt2a[j] = __float2bfloat16((n < HID_ && k < HID_) ? Wa2[k * HID_ + n] : 0.f);
    } else if (i < s0 + s1 + s2) {
        int j = i - s0 - s1, n = j / 3072, k = j - n * 3072;
        Wt1s[j] = __float2bfloat16(n < HID_ ? Ws1[k * HID_ + n] : 0.f);
    } else if (i < s0 + s1 + s2 + s3) {
        int j = i - s0 - s1 - s2, n = j / 160, k = j - n * 160;
        Wt2s[j] = __float2bfloat16((n < HID_ && k < HID_) ? Ws2[k * HID_ + n] : 0.f);
    } else if (i < s0 + s1 + s2 + s3 + 1024) {
        zerobuf[i - s0 - s1 - s2 - s3] = 0.f;    // 4 KB zero row
    }
}

// attn MLP: 1024 -> 150 relu -> 150 relu -> 1, 64 rows/block, 4 waves.
template<int K1>
__global__ __launch_bounds__(256, 2)
void mlp_mfma(const float* __restrict__ xin,
              const __hip_bfloat16* __restrict__ Wt1, const float* __restrict__ b1,
              const __hip_bfloat16* __restrict__ Wt2, const float* __restrict__ b2,
              const float* __restrict__ W3, const float* __restrict__ b3,
              float* __restrict__ outp)
{
    constexpr int NC  = K1 / 64;
    constexpr int ACH = 64 * 64 * 4;
    constexpr int BCH = 160 * 64 * 2;
    __shared__ __align__(16) char smem[2 * ACH + 2 * BCH];

    const int tid  = threadIdx.x;
    const int lane = tid & 63;
    const int w    = tid >> 6;
    const int rg   = w >> 1;
    const int cg   = w & 1;
    const int lr   = lane & 15;
    const int hi   = lane >> 4;

    const long long row0 = (long long)blockIdx.x * MROWS;

    auto stageA = [&](int bi, int c) {
        char* dst = smem + bi * ACH;
#pragma unroll
        for (int j = 0; j < 4; ++j) {
            const int row  = (w * 4 + j) * 4 + (lane >> 4);
            const int slot = (lane & 15) ^ (row & 7);
            gload16(xin + (row0 + row) * (long long)K1 + c * 64 + slot * 4,
                    dst + (w * 4 + j) * 1024);
        }
    };
    auto stageB = [&](int bi, int c) {
        char* dst = smem + 2 * ACH + bi * BCH;
#pragma unroll
        for (int j = 0; j < 5; ++j) {
            const int nrow = (w * 5 + j) * 8 + (lane >> 3);
            const int slot = (lane & 7) ^ (nrow & 7);
            gload16(Wt1 + (long long)nrow * K1 + c * 64 + slot * 8,
                    dst + (w * 5 + j) * 1024);
        }
    };

    f32x4 acc[2][5];
#pragma unroll
    for (int rt = 0; rt < 2; ++rt)
#pragma unroll
        for (int nt = 0; nt < 5; ++nt) acc[rt][nt] = (f32x4){0.f, 0.f, 0.f, 0.f};

    stageA(0, 0);
    stageB(0, 0);

    for (int c = 0; c < NC; ++c) {
        __syncthreads();
        if (c + 1 < NC) { stageA((c + 1) & 1, c + 1); stageB((c + 1) & 1, c + 1); }
        const int bi = c & 1;
        const char* sA = smem + bi * ACH;
        const char* sB = smem + 2 * ACH + bi * BCH;
#pragma unroll
        for (int ks = 0; ks < 2; ++ks) {
            short8 bfr[5];
#pragma unroll
            for (int nt = 0; nt < 5; ++nt) {
                const int nrow = cg * 80 + nt * 16 + lr;
                const int slot = (ks * 4 + hi) ^ (nrow & 7);
                bfr[nt] = *(const short8*)(sB + nrow * 128 + slot * 16);
            }
#pragma unroll
            for (int rt = 0; rt < 2; ++rt) {
                const int r = rg * 32 + rt * 16 + lr;
                const int s0i = (ks * 8 + hi * 2) ^ (r & 7);
                const int s1i = (ks * 8 + hi * 2 + 1) ^ (r & 7);
                float4 a0 = *(const float4*)(sA + r * 256 + s0i * 16);
                float4 a1 = *(const float4*)(sA + r * 256 + s1i * 16);
                short8 afr = pack8(a0, a1);
#pragma unroll
                for (int nt = 0; nt < 5; ++nt)
                    acc[rt][nt] = __builtin_amdgcn_mfma_f32_16x16x32_bf16(
                        afr, bfr[nt], acc[rt][nt], 0, 0, 0);
            }
        }
    }
    __syncthreads();

    __hip_bfloat16* hl = (__hip_bfloat16*)smem;

#pragma unroll
    for (int nt = 0; nt < 5; ++nt) {
        const int ch = cg * 80 + nt * 16 + lr;
        const float bb = (ch < HID_) ? b1[ch] : 0.f;
#pragma unroll
        for (int rt = 0; rt < 2; ++rt)
#pragma unroll
            for (int r4 = 0; r4 < 4; ++r4) {
                const int row = rg * 32 + rt * 16 + hi * 4 + r4;
                float h = acc[rt][nt][r4] + bb;
                hl[row * LSTR + ch] = __float2bfloat16(h > 0.f ? h : 0.f);
            }
    }
    __syncthreads();

    f32x4 acc2[2][5];
#pragma unroll
    for (int rt = 0; rt < 2; ++rt)
#pragma unroll
        for (int nt = 0; nt < 5; ++nt) acc2[rt][nt] = (f32x4){0.f, 0.f, 0.f, 0.f};

#pragma unroll
    for (int ks = 0; ks < 5; ++ks) {
        const int k0 = ks * 32 + hi * 8;
        short8 bfr[5];
#pragma unroll
        for (int nt = 0; nt < 5; ++nt)
            bfr[nt] = *(const short8*)(Wt2 + (cg * 80 + nt * 16 + lr) * NPAD + k0);
#pragma unroll
        for (int rt = 0; rt < 2; ++rt) {
            short8 afr = *(const short8*)&hl[(rg * 32 + rt * 16 + lr) * LSTR + k0];
#pragma unroll
            for (int nt = 0; nt < 5; ++nt)
                acc2[rt][nt] = __builtin_amdgcn_mfma_f32_16x16x32_bf16(
                    afr, bfr[nt], acc2[rt][nt], 0, 0, 0);
        }
    }
    __syncthreads();

#pragma unroll
    for (int nt = 0; nt < 5; ++nt) {
        const int ch = cg * 80 + nt * 16 + lr;
        const float bb = (ch < HID_) ? b2[ch] : 0.f;
#pragma unroll
        for (int rt = 0; rt < 2; ++rt)
#pragma unroll
            for (int r4 = 0; r4 < 4; ++r4) {
                const int row = rg * 32 + rt * 16 + hi * 4 + r4;
                float h = acc2[rt][nt][r4] + bb;
                hl[row * LSTR + ch] = __float2bfloat16(h > 0.f ? h : 0.f);
            }
    }
    __syncthreads();

    {
        const int row = tid >> 2, quad = tid & 3;
        const int kb = quad * 38;
        const int ke = (kb + 38 > HID_) ? HID_ : kb + 38;
        float s = 0.f;
        for (int k = kb; k < ke; ++k)
            s += __bfloat162float(hl[row * LSTR + k]) * W3[k];
        s += __shfl_xor(s, 1);
        s += __shfl_xor(s, 2);
        if (quad == 0) outp[row0 + row] = s + b3[0];
    }
}

// ---- weighted prefix sum over tokens (reference's cumsum trick) ----
__global__ __launch_bounds__(256)
void wsum_tiles(const float* __restrict__ x, const float* __restrict__ attn,
                float* __restrict__ P)
{
    const int b = blockIdx.x >> 5, tile = blockIdx.x & 31, q = threadIdx.x;
    const float* xb = x + ((long long)b * T_ + tile * 64) * E_ + q * 4;
    const float* ab = attn + b * T_ + tile * 64;
    f32x4 a0 = (f32x4){0.f, 0.f, 0.f, 0.f}, a1 = a0;
#pragma unroll 8
    for (int t = 0; t < 64; t += 2) {
        a0 += ab[t]     * *(const f32x4*)(xb + (long long)t * E_);
        a1 += ab[t + 1] * *(const f32x4*)(xb + (long long)(t + 1) * E_);
    }
    *(f32x4*)(P + ((long long)(b * 32 + tile)) * E_ + q * 4) = a0 + a1;
}

__global__ __launch_bounds__(256)
void wcumsum(const float* __restrict__ x, const float* __restrict__ attn,
             const float* __restrict__ P, float* __restrict__ csum)
{
    const int b = blockIdx.x >> 5, tile = blockIdx.x & 31, q = threadIdx.x;
    f32x4 pfx = (f32x4){0.f, 0.f, 0.f, 0.f};
    for (int tau = 0; tau < tile; ++tau)
        pfx += *(const f32x4*)(P + ((long long)(b * 32 + tau)) * E_ + q * 4);
    const float* xb = x + ((long long)b * T_ + tile * 64) * E_ + q * 4;
    float*       cb = csum + ((long long)b * T_ + tile * 64) * E_ + q * 4;
    const float* ab = attn + b * T_ + tile * 64;
    f32x4 acc = pfx;
#pragma unroll 4
    for (int t = 0; t < 64; ++t) {
        acc += ab[t] * *(const f32x4*)(xb + (long long)t * E_);
        *(f32x4*)(cb + (long long)t * E_) = acc;
    }
}

// Fused span construction + score MLP. 64 spans/block, 512 threads (8 waves).
// A-construction pipelined one FULL phase deep: loads(c+2) issued in phase c,
// emit(c+1) [nt-stores + ds_write] at TOP of phase c -> gather latency is
// covered by an entire phase. Spanout stores are non-temporal (keep L3 for
// csum/x gathers). Counted vmcnt(6) keeps loads/stores in flight across
// barriers while guaranteeing own-wave B-DMAs landed.
__global__ __launch_bounds__(512, 4)
void span_score(const float* __restrict__ x, const float* __restrict__ csum,
                const float* __restrict__ zrow,
                const int* __restrict__ starts, const int* __restrict__ lengths,
                const int* __restrict__ nspans,
                const __hip_bfloat16* __restrict__ Wt1, const float* __restrict__ b1,
                const __hip_bfloat16* __restrict__ Wt2, const float* __restrict__ b2,
                const float* __restrict__ W3, const float* __restrict__ b3,
                float* __restrict__ spanout, float* __restrict__ scoreout)
{
    // layout: sA dbuf 2x8KB @0 ; sB dbuf 2x20KB @16384 ; meta @57344
    __shared__ __align__(16) char smem[58112];
    int* stL = (int*)(smem + 57344);
    int* enL = (int*)(smem + 57600);
    int* bL  = (int*)(smem + 57856);

    const int tid  = threadIdx.x;
    const int lane = tid & 63;
    const int w    = tid >> 6;     // 0..7
    const int rg   = w >> 1;       // 0..3 : rows rg*16..+16
    const int cg   = w & 1;        // cols cg*80..+80
    const int lr   = lane & 15;
    const int hi   = lane >> 4;

    // bijective XCD-aware swizzle over 500 blocks
    int bid = blockIdx.x;
    {
        const int qq = 500 / 8, rr = 500 % 8;
        const int xcd = bid % 8, i = bid / 8;
        bid = (xcd < rr ? xcd * (qq + 1) : rr * (qq + 1) + (xcd - rr) * qq) + i;
    }
    const int span0 = bid * 64;

    if (tid < 64) {
        const int sp = span0 + tid;
        const int b  = sp / S_;
        const int s  = sp - b * S_;
        const bool val = s < nspans[b];
        const int st = val ? starts[sp] : 0;
        stL[tid] = st;
        enL[tid] = val ? (st + lengths[sp]) : -1;
        bL[tid]  = b;
    }
    __syncthreads();

    const int r    = tid >> 3;     // constructor row 0..63
    const int q    = tid & 7;      // 8 floats per thread
    const int st_r = stL[r];
    const int en_r = enL[r];       // -1 for invalid spans
    const bool valid = en_r >= st_r;
    const long long sp_r = span0 + r;
    const float* xb = x    + (long long)bL[r] * T_ * E_;
    const float* cb = csum + (long long)bL[r] * T_ * E_;

    const float* px_st = valid ? xb + (long long)st_r * E_ : zrow;
    const float* px_en = valid ? xb + (long long)en_r * E_ : zrow;
    const float* pc_en = valid ? cb + (long long)en_r * E_ : zrow;
    const float* pc_st = (valid && st_r > 0) ? cb + (long long)(st_r - 1) * E_ : zrow;

    auto srcs = [&](int c, const float*& s1, const float*& s2) {
        s1 = (c < 16) ? px_st : ((c < 32) ? px_en : pc_en);
        s2 = (c < 32) ? zrow : pc_st;
    };
    auto ldreg = [&](int c, f32x4& l0, f32x4& l1, f32x4& l2, f32x4& l3) {
        const float *s1, *s2;
        srcs(c, s1, s2);
        const int off = (c & 15) * 64 + q * 8;
        l0 = *(const f32x4*)(s1 + off);
        l1 = *(const f32x4*)(s1 + off + 4);
        l2 = *(const f32x4*)(s2 + off);
        l3 = *(const f32x4*)(s2 + off + 4);
    };
    auto emit = [&](int bi, int c, f32x4 l0, f32x4 l1, f32x4 l2, f32x4 l3) {
        f32x4 v0 = l0 - l2, v1 = l1 - l3;
        float* orow = spanout + sp_r * (3 * E_) + c * 64 + q * 8;
        __builtin_nontemporal_store(v0, (f32x4*)orow);        // never re-read:
        __builtin_nontemporal_store(v1, (f32x4*)(orow + 4));  // bypass L2/L3
        *(short8*)(smem + bi * 8192 + r * 128 + ((q ^ (r & 7)) * 16)) = pack8v(v0, v1);
    };
    auto stageB = [&](int bi, int c) {
        char* dst = smem + 16384 + bi * 20480;
#pragma unroll
        for (int j = 0; j < 3; ++j) {
            const int idx = w * 3 + j;      // 20 x 1KB pieces over 8 waves
            if (idx < 20) {
                const int nrow = idx * 8 + (lane >> 3);
                const int slot = (lane & 7) ^ (nrow & 7);
                gload16(Wt1 + (long long)nrow * GI_ + c * 64 + slot * 8,
                        dst + idx * 1024);
            }
        }
    };

    // ---------------- stage 1: 3072 -> 160 ----------------
    f32x4 acc[5];
#pragma unroll
    for (int nt = 0; nt < 5; ++nt) acc[nt] = (f32x4){0.f, 0.f, 0.f, 0.f};

    f32x4 pA0, pA1, pA2, pA3;   // ping
    f32x4 pB0, pB1, pB2, pB3;   // pong

    // prologue: B(0) DMA; A(0) -> emit into buf0; A(1) into pong regs
    stageB(0, 0);
    ldreg(0, pA0, pA1, pA2, pA3);
    emit(0, 0, pA0, pA1, pA2, pA3);     // implicit wait drains loads(0)+DMAs(0)
    ldreg(1, pB0, pB1, pB2, pB3);

    auto phase = [&](int c, f32x4& u0, f32x4& u1, f32x4& u2, f32x4& u3,
                     f32x4& f0, f32x4& f1, f32x4& f2, f32x4& f3) {
        // entry: sA[c&1], sB[c&1] ready; u-regs hold loads for chunk c+1
        asm volatile("s_waitcnt vmcnt(6) lgkmcnt(0)" ::: "memory");
        __builtin_amdgcn_s_barrier();
        const int bi = c & 1;
        if (c + 1 < 48) {
            stageB(bi ^ 1, c + 1);
            emit(bi ^ 1, c + 1, u0, u1, u2, u3);  // waits u-loads (older than DMAs)
        }
        if (c + 2 < 48) ldreg(c + 2, f0, f1, f2, f3);  // fire for phase c+1
        const char* sAc = smem + bi * 8192;
        const char* sBc = smem + 16384 + bi * 20480;
#pragma unroll
        for (int ks = 0; ks < 2; ++ks) {
            short8 bfr[5];
#pragma unroll
            for (int nt = 0; nt < 5; ++nt) {
                const int nrow = cg * 80 + nt * 16 + lr;
                const int slot = (ks * 4 + hi) ^ (nrow & 7);
                bfr[nt] = *(const short8*)(sBc + nrow * 128 + slot * 16);
            }
            const int r2 = rg * 16 + lr;
            const int sl = (ks * 4 + hi) ^ (r2 & 7);
            short8 afr = *(const short8*)(sAc + r2 * 128 + sl * 16);
#pragma unroll
            for (int nt = 0; nt < 5; ++nt)
                acc[nt] = __builtin_amdgcn_mfma_f32_16x16x32_bf16(
                    afr, bfr[nt], acc[nt], 0, 0, 0);
        }
    };

    for (int cc = 0; cc < 48; cc += 2) {
        phase(cc,     pB0, pB1, pB2, pB3, pA0, pA1, pA2, pA3);
        phase(cc + 1, pA0, pA1, pA2, pA3, pB0, pB1, pB2, pB3);
    }
    asm volatile("s_waitcnt lgkmcnt(0)" ::: "memory");
    __builtin_amdgcn_s_barrier();

    __hip_bfloat16* hl = (__hip_bfloat16*)smem;   // 21.5 KB alias

#pragma unroll
    for (int nt = 0; nt < 5; ++nt) {
        const int ch = cg * 80 + nt * 16 + lr;
        const float bb = (ch < HID_) ? b1[ch] : 0.f;
#pragma unroll
        for (int r4 = 0; r4 < 4; ++r4) {
            const int row = rg * 16 + hi * 4 + r4;
            float h = acc[nt][r4] + bb;
            hl[row * LSTR + ch] = __float2bfloat16(h > 0.f ? h : 0.f);
        }
    }
    __syncthreads();

    // ---------------- stage 2: 160 -> 160 ----------------
    f32x4 acc2[5];
#pragma unroll
    for (int nt = 0; nt < 5; ++nt) acc2[nt] = (f32x4){0.f, 0.f, 0.f, 0.f};

#pragma unroll
    for (int ks = 0; ks < 5; ++ks) {
        const int k0 = ks * 32 + hi * 8;
        short8 bfr[5];
#pragma unroll
        for (int nt = 0; nt < 5; ++nt)
            bfr[nt] = *(const short8*)(Wt2 + (cg * 80 + nt * 16 + lr) * NPAD + k0);
        short8 afr = *(const short8*)&hl[(rg * 16 + lr) * LSTR + k0];
#pragma unroll
        for (int nt = 0; nt < 5; ++nt)
            acc2[nt] = __builtin_amdgcn_mfma_f32_16x16x32_bf16(
                afr, bfr[nt], acc2[nt], 0, 0, 0);
    }
    __syncthreads();

#pragma unroll
    for (int nt = 0; nt < 5; ++nt) {
        const int ch = cg * 80 + nt * 16 + lr;
        const float bb = (ch < HID_) ? b2[ch] : 0.f;
#pragma unroll
        for (int r4 = 0; r4 < 4; ++r4) {
            const int row = rg * 16 + hi * 4 + r4;
            float h = acc2[nt][r4] + bb;
            hl[row * LSTR + ch] = __float2bfloat16(h > 0.f ? h : 0.f);
        }
    }
    __syncthreads();

    // ---------------- stage 3: 150 -> 1 (8 threads/row) ----------------
    {
        const int row = tid >> 3, oct = tid & 7;
        const int kb = oct * 19;
        const int ke = (kb + 19 > HID_) ? HID_ : kb + 19;
        float s = 0.f;
        for (int k = kb; k < ke; ++k)
            s += __bfloat162float(hl[row * LSTR + k]) * W3[k];
        s += __shfl_xor(s, 1);
        s += __shfl_xor(s, 2);
        s += __shfl_xor(s, 4);
        if (oct == 0) scoreout[span0 + row] = s + b3[0];
    }
}

extern "C" void kernel_launch(void* const* d_in, const int* in_sizes, int n_in,
                              void* d_out, int out_size, void* d_ws, size_t ws_size,
                              hipStream_t stream) {
    const float* x       = (const float*)d_in[0];
    const int*   starts  = (const int*)d_in[1];
    const int*   lengths = (const int*)d_in[2];
    const int*   nspans  = (const int*)d_in[3];
    const float* Wa1 = (const float*)d_in[4];
    const float* ba1 = (const float*)d_in[5];
    const float* Wa2 = (const float*)d_in[6];
    const float* ba2 = (const float*)d_in[7];
    const float* Wa3 = (const float*)d_in[8];
    const float* ba3 = (const float*)d_in[9];
    const float* Ws1 = (const float*)d_in[10];
    const float* bs1 = (const float*)d_in[11];
    const float* Ws2 = (const float*)d_in[12];
    const float* bs2 = (const float*)d_in[13];
    const float* Ws3 = (const float*)d_in[14];
    const float* bs3 = (const float*)d_in[15];

    float* out        = (float*)d_out;                       // span_emb [B,S,3E]
    float* out_scores = out + (long long)B_ * S_ * 3 * E_;   // scores [B,S]

    char* ws = (char*)d_ws;
    float*          attn    = (float*)ws;                       // 131072 B
    __hip_bfloat16* Wt1a    = (__hip_bfloat16*)(ws + 131072);   // 160*1024*2
    __hip_bfloat16* Wt2a    = (__hip_bfloat16*)(ws + 458752);   // 160*160*2
    __hip_bfloat16* Wt1s    = (__hip_bfloat16*)(ws + 509952);   // 160*3072*2
    __hip_bfloat16* Wt2s    = (__hip_bfloat16*)(ws + 1492992);  // 160*160*2
    float*          zerobuf = (float*)(ws + 1544192);           // 4 KB zeros
    float*          Ptile   = (float*)(ws + 2097152);           // 2 MB
    float*          csum    = (float*)(ws + 4194304);           // 134 MB

    // 0) weight transposes + zero-row init
    transpose_all<<<2765, 256, 0, stream>>>(Wa1, Wa2, Ws1, Ws2,
                                            Wt1a, Wt2a, Wt1s, Wt2s, zerobuf);

    // 1) attention score per token (32768 rows, 512 blocks)
    mlp_mfma<E_><<<(B_ * T_) / MROWS, 256, 0, stream>>>
        (x, Wt1a, ba1, Wt2a, ba2, Wa3, ba3, attn);

    // 2) weighted prefix sums: tile sums then full csum
    wsum_tiles<<<B_ * 32, 256, 0, stream>>>(x, attn, Ptile);
    wcumsum   <<<B_ * 32, 256, 0, stream>>>(x, attn, Ptile, csum);

    // 3) fused span construction + mention-score MLP (500 blocks)
    span_score<<<500, 512, 0, stream>>>
        (x, csum, zerobuf, starts, lengths, nspans,
         Wt1s, bs1, Wt2s, bs2, Ws3, bs3, out, out_scores);
}

// Round 18
// 254.765 us; speedup vs baseline: 1.1793x; 1.0365x over previous
//
#include <hip/hip_runtime.h>
#include <hip/hip_bf16.h>

#define B_   16
#define T_   2048
#define E_   1024
#define S_   2000
#define HID_ 150
#define GI_  3072

typedef __attribute__((ext_vector_type(8))) short short8;   // 8 bf16 (4 VGPRs)
typedef __attribute__((ext_vector_type(4))) float f32x4;

constexpr int NPAD  = 160;   // HID padded to 10 MFMA col-tiles
constexpr int LSTR  = 168;   // hl row stride (bf16): 336 B
constexpr int MROWS = 64;    // rows per MLP block

__device__ __forceinline__ void gload16(const void* gsrc, void* ldst) {
    __builtin_amdgcn_global_load_lds(
        (const __attribute__((address_space(1))) unsigned int*)gsrc,
        (__attribute__((address_space(3))) unsigned int*)ldst,
        16, 0, 0);   // 16B/lane, wave-uniform LDS base + lane*16
}

__device__ __forceinline__ short8 pack8(float4 a, float4 b) {
    union { __hip_bfloat162 h[4]; short8 s; } u;
    u.h[0] = __float22bfloat162_rn(make_float2(a.x, a.y));
    u.h[1] = __float22bfloat162_rn(make_float2(a.z, a.w));
    u.h[2] = __float22bfloat162_rn(make_float2(b.x, b.y));
    u.h[3] = __float22bfloat162_rn(make_float2(b.z, b.w));
    return u.s;
}

__device__ __forceinline__ short8 pack8v(f32x4 a, f32x4 b) {
    union { __hip_bfloat162 h[4]; short8 s; } u;
    u.h[0] = __float22bfloat162_rn(make_float2(a.x, a.y));
    u.h[1] = __float22bfloat162_rn(make_float2(a.z, a.w));
    u.h[2] = __float22bfloat162_rn(make_float2(b.x, b.y));
    u.h[3] = __float22bfloat162_rn(make_float2(b.z, b.w));
    return u.s;
}

__device__ __forceinline__ void bf16x8_f32(short8 m, f32x4& lo, f32x4& hi) {
    union { short8 s; __hip_bfloat162 h[4]; } u; u.s = m;
    float2 f0 = __bfloat1622float2(u.h[0]);
    float2 f1 = __bfloat1622float2(u.h[1]);
    float2 f2 = __bfloat1622float2(u.h[2]);
    float2 f3 = __bfloat1622float2(u.h[3]);
    lo = (f32x4){f0.x, f0.y, f1.x, f1.y};
    hi = (f32x4){f2.x, f2.y, f3.x, f3.y};
}

// Weight transposes (f32 [K][150] -> bf16 [160][K], zero-padded) + ws zero-row.
__global__ __launch_bounds__(256)
void transpose_all(const float* __restrict__ Wa1, const float* __restrict__ Wa2,
                   const float* __restrict__ Ws1, const float* __restrict__ Ws2,
                   __hip_bfloat16* __restrict__ Wt1a, __hip_bfloat16* __restrict__ Wt2a,
                   __hip_bfloat16* __restrict__ Wt1s, __hip_bfloat16* __restrict__ Wt2s,
                   float* __restrict__ zerobuf)
{
    const int s0 = 160 * 1024, s1 = 160 * 160, s2 = 160 * 3072, s3 = 160 * 160;
    int i = blockIdx.x * 256 + threadIdx.x;
    if (i < s0) {
        int n = i >> 10, k = i & 1023;
        Wt1a[i] = __float2bfloat16(n < HID_ ? Wa1[k * HID_ + n] : 0.f);
    } else if (i < s0 + s1) {
        int j = i - s0, n = j / 160, k = j - n * 160;
        Wt2a[j] = __float2bfloat16((n < HID_ && k < HID_) ? Wa2[k * HID_ + n] : 0.f);
    } else if (i < s0 + s1 + s2) {
        int j = i - s0 - s1, n = j / 3072, k = j - n * 3072;
        Wt1s[j] = __float2bfloat16(n < HID_ ? Ws1[k * HID_ + n] : 0.f);
    } else if (i < s0 + s1 + s2 + s3) {
        int j = i - s0 - s1 - s2, n = j / 160, k = j - n * 160;
        Wt2s[j] = __float2bfloat16((n < HID_ && k < HID_) ? Ws2[k * HID_ + n] : 0.f);
    } else if (i < s0 + s1 + s2 + s3 + 1024) {
        zerobuf[i - s0 - s1 - s2 - s3] = 0.f;    // 4 KB zeros (f32 or bf16 view)
    }
}

// attn MLP: 1024 -> 150 relu -> 150 relu -> 1, 64 rows/block, 4 waves.
template<int K1>
__global__ __launch_bounds__(256, 2)
void mlp_mfma(const float* __restrict__ xin,
              const __hip_bfloat16* __restrict__ Wt1, const float* __restrict__ b1,
              const __hip_bfloat16* __restrict__ Wt2, const float* __restrict__ b2,
              const float* __restrict__ W3, const float* __restrict__ b3,
              float* __restrict__ outp)
{
    constexpr int NC  = K1 / 64;
    constexpr int ACH = 64 * 64 * 4;
    constexpr int BCH = 160 * 64 * 2;
    __shared__ __align__(16) char smem[2 * ACH + 2 * BCH];

    const int tid  = threadIdx.x;
    const int lane = tid & 63;
    const int w    = tid >> 6;
    const int rg   = w >> 1;
    const int cg   = w & 1;
    const int lr   = lane & 15;
    const int hi   = lane >> 4;

    const long long row0 = (long long)blockIdx.x * MROWS;

    auto stageA = [&](int bi, int c) {
        char* dst = smem + bi * ACH;
#pragma unroll
        for (int j = 0; j < 4; ++j) {
            const int row  = (w * 4 + j) * 4 + (lane >> 4);
            const int slot = (lane & 15) ^ (row & 7);
            gload16(xin + (row0 + row) * (long long)K1 + c * 64 + slot * 4,
                    dst + (w * 4 + j) * 1024);
        }
    };
    auto stageB = [&](int bi, int c) {
        char* dst = smem + 2 * ACH + bi * BCH;
#pragma unroll
        for (int j = 0; j < 5; ++j) {
            const int nrow = (w * 5 + j) * 8 + (lane >> 3);
            const int slot = (lane & 7) ^ (nrow & 7);
            gload16(Wt1 + (long long)nrow * K1 + c * 64 + slot * 8,
                    dst + (w * 5 + j) * 1024);
        }
    };

    f32x4 acc[2][5];
#pragma unroll
    for (int rt = 0; rt < 2; ++rt)
#pragma unroll
        for (int nt = 0; nt < 5; ++nt) acc[rt][nt] = (f32x4){0.f, 0.f, 0.f, 0.f};

    stageA(0, 0);
    stageB(0, 0);

    for (int c = 0; c < NC; ++c) {
        __syncthreads();
        if (c + 1 < NC) { stageA((c + 1) & 1, c + 1); stageB((c + 1) & 1, c + 1); }
        const int bi = c & 1;
        const char* sA = smem + bi * ACH;
        const char* sB = smem + 2 * ACH + bi * BCH;
#pragma unroll
        for (int ks = 0; ks < 2; ++ks) {
            short8 bfr[5];
#pragma unroll
            for (int nt = 0; nt < 5; ++nt) {
                const int nrow = cg * 80 + nt * 16 + lr;
                const int slot = (ks * 4 + hi) ^ (nrow & 7);
                bfr[nt] = *(const short8*)(sB + nrow * 128 + slot * 16);
            }
#pragma unroll
            for (int rt = 0; rt < 2; ++rt) {
                const int r = rg * 32 + rt * 16 + lr;
                const int s0i = (ks * 8 + hi * 2) ^ (r & 7);
                const int s1i = (ks * 8 + hi * 2 + 1) ^ (r & 7);
                float4 a0 = *(const float4*)(sA + r * 256 + s0i * 16);
                float4 a1 = *(const float4*)(sA + r * 256 + s1i * 16);
                short8 afr = pack8(a0, a1);
#pragma unroll
                for (int nt = 0; nt < 5; ++nt)
                    acc[rt][nt] = __builtin_amdgcn_mfma_f32_16x16x32_bf16(
                        afr, bfr[nt], acc[rt][nt], 0, 0, 0);
            }
        }
    }
    __syncthreads();

    __hip_bfloat16* hl = (__hip_bfloat16*)smem;

#pragma unroll
    for (int nt = 0; nt < 5; ++nt) {
        const int ch = cg * 80 + nt * 16 + lr;
        const float bb = (ch < HID_) ? b1[ch] : 0.f;
#pragma unroll
        for (int rt = 0; rt < 2; ++rt)
#pragma unroll
            for (int r4 = 0; r4 < 4; ++r4) {
                const int row = rg * 32 + rt * 16 + hi * 4 + r4;
                float h = acc[rt][nt][r4] + bb;
                hl[row * LSTR + ch] = __float2bfloat16(h > 0.f ? h : 0.f);
            }
    }
    __syncthreads();

    f32x4 acc2[2][5];
#pragma unroll
    for (int rt = 0; rt < 2; ++rt)
#pragma unroll
        for (int nt = 0; nt < 5; ++nt) acc2[rt][nt] = (f32x4){0.f, 0.f, 0.f, 0.f};

#pragma unroll
    for (int ks = 0; ks < 5; ++ks) {
        const int k0 = ks * 32 + hi * 8;
        short8 bfr[5];
#pragma unroll
        for (int nt = 0; nt < 5; ++nt)
            bfr[nt] = *(const short8*)(Wt2 + (cg * 80 + nt * 16 + lr) * NPAD + k0);
#pragma unroll
        for (int rt = 0; rt < 2; ++rt) {
            short8 afr = *(const short8*)&hl[(rg * 32 + rt * 16 + lr) * LSTR + k0];
#pragma unroll
            for (int nt = 0; nt < 5; ++nt)
                acc2[rt][nt] = __builtin_amdgcn_mfma_f32_16x16x32_bf16(
                    afr, bfr[nt], acc2[rt][nt], 0, 0, 0);
        }
    }
    __syncthreads();

#pragma unroll
    for (int nt = 0; nt < 5; ++nt) {
        const int ch = cg * 80 + nt * 16 + lr;
        const float bb = (ch < HID_) ? b2[ch] : 0.f;
#pragma unroll
        for (int rt = 0; rt < 2; ++rt)
#pragma unroll
            for (int r4 = 0; r4 < 4; ++r4) {
                const int row = rg * 32 + rt * 16 + hi * 4 + r4;
                float h = acc2[rt][nt][r4] + bb;
                hl[row * LSTR + ch] = __float2bfloat16(h > 0.f ? h : 0.f);
            }
    }
    __syncthreads();

    {
        const int row = tid >> 2, quad = tid & 3;
        const int kb = quad * 38;
        const int ke = (kb + 38 > HID_) ? HID_ : kb + 38;
        float s = 0.f;
        for (int k = kb; k < ke; ++k)
            s += __bfloat162float(hl[row * LSTR + k]) * W3[k];
        s += __shfl_xor(s, 1);
        s += __shfl_xor(s, 2);
        if (quad == 0) outp[row0 + row] = s + b3[0];
    }
}

// ---- weighted prefix sum (reference's cumsum trick); csum stored bf16 ----
__global__ __launch_bounds__(256)
void wsum_tiles(const float* __restrict__ x, const float* __restrict__ attn,
                float* __restrict__ P)
{
    const int b = blockIdx.x >> 5, tile = blockIdx.x & 31, q = threadIdx.x;
    const float* xb = x + ((long long)b * T_ + tile * 64) * E_ + q * 4;
    const float* ab = attn + b * T_ + tile * 64;
    f32x4 a0 = (f32x4){0.f, 0.f, 0.f, 0.f}, a1 = a0;
#pragma unroll 8
    for (int t = 0; t < 64; t += 2) {
        a0 += ab[t]     * *(const f32x4*)(xb + (long long)t * E_);
        a1 += ab[t + 1] * *(const f32x4*)(xb + (long long)(t + 1) * E_);
    }
    *(f32x4*)(P + ((long long)(b * 32 + tile)) * E_ + q * 4) = a0 + a1;
}

// scan in f32, store bf16 (halves bytes; x+csum then fits 256MB L3)
__global__ __launch_bounds__(256)
void wcumsum(const float* __restrict__ x, const float* __restrict__ attn,
             const float* __restrict__ P, __hip_bfloat16* __restrict__ csum)
{
    const int b = blockIdx.x >> 5, tile = blockIdx.x & 31, q = threadIdx.x;
    f32x4 pfx = (f32x4){0.f, 0.f, 0.f, 0.f};
    for (int tau = 0; tau < tile; ++tau)
        pfx += *(const f32x4*)(P + ((long long)(b * 32 + tau)) * E_ + q * 4);
    const float* xb = x + ((long long)b * T_ + tile * 64) * E_ + q * 4;
    __hip_bfloat16* cb = csum + ((long long)b * T_ + tile * 64) * E_ + q * 4;
    const float* ab = attn + b * T_ + tile * 64;
    f32x4 acc = pfx;
#pragma unroll 4
    for (int t = 0; t < 64; ++t) {
        acc += ab[t] * *(const f32x4*)(xb + (long long)t * E_);
        union { __hip_bfloat162 h[2]; uint2 u; } cv;
        cv.h[0] = __float22bfloat162_rn(make_float2(acc.x, acc.y));
        cv.h[1] = __float22bfloat162_rn(make_float2(acc.z, acc.w));
        *(uint2*)(cb + (long long)t * E_) = cv.u;
    }
}

// Fused span construction + score MLP. 64 spans/block, 512 threads (8 waves).
// A pipelined one full phase deep (loads c+2 in phase c, emit c+1 at top of
// phase c); copy chunks load f32 x-rows, sum chunks load bf16 csum rows
// (L3-resident). nt-stores for spanout. vmcnt(4): 2 loads + 2 stores follow
// the B-DMAs each phase.
__global__ __launch_bounds__(512, 4)
void span_score(const float* __restrict__ x, const __hip_bfloat16* __restrict__ csum,
                const float* __restrict__ zrow,
                const int* __restrict__ starts, const int* __restrict__ lengths,
                const int* __restrict__ nspans,
                const __hip_bfloat16* __restrict__ Wt1, const float* __restrict__ b1,
                const __hip_bfloat16* __restrict__ Wt2, const float* __restrict__ b2,
                const float* __restrict__ W3, const float* __restrict__ b3,
                float* __restrict__ spanout, float* __restrict__ scoreout)
{
    __shared__ __align__(16) char smem[58112];
    int* stL = (int*)(smem + 57344);
    int* enL = (int*)(smem + 57600);
    int* bL  = (int*)(smem + 57856);

    const int tid  = threadIdx.x;
    const int lane = tid & 63;
    const int w    = tid >> 6;
    const int rg   = w >> 1;
    const int cg   = w & 1;
    const int lr   = lane & 15;
    const int hi   = lane >> 4;

    int bid = blockIdx.x;
    {
        const int qq = 500 / 8, rr = 500 % 8;
        const int xcd = bid % 8, i = bid / 8;
        bid = (xcd < rr ? xcd * (qq + 1) : rr * (qq + 1) + (xcd - rr) * qq) + i;
    }
    const int span0 = bid * 64;

    if (tid < 64) {
        const int sp = span0 + tid;
        const int b  = sp / S_;
        const int s  = sp - b * S_;
        const bool val = s < nspans[b];
        const int st = val ? starts[sp] : 0;
        stL[tid] = st;
        enL[tid] = val ? (st + lengths[sp]) : -1;
        bL[tid]  = b;
    }
    __syncthreads();

    const int r    = tid >> 3;
    const int q    = tid & 7;
    const int st_r = stL[r];
    const int en_r = enL[r];
    const bool valid = en_r >= st_r;
    const long long sp_r = span0 + r;
    const float* xb = x + (long long)bL[r] * T_ * E_;
    const __hip_bfloat16* cbh = csum + (long long)bL[r] * T_ * E_;
    const __hip_bfloat16* zrh = (const __hip_bfloat16*)zrow;

    const float* px_st = valid ? xb + (long long)st_r * E_ : zrow;
    const float* px_en = valid ? xb + (long long)en_r * E_ : zrow;
    const __hip_bfloat16* pc_en = valid ? cbh + (long long)en_r * E_ : zrh;
    const __hip_bfloat16* pc_st = (valid && st_r > 0) ? cbh + (long long)(st_r - 1) * E_ : zrh;

    auto ldreg = [&](int c, f32x4& l0, f32x4& l1, short8& m0, short8& m1) {
        const int off = (c & 15) * 64 + q * 8;
        if (c < 32) {
            const float* s1 = (c < 16) ? px_st : px_en;
            l0 = *(const f32x4*)(s1 + off);
            l1 = *(const f32x4*)(s1 + off + 4);
        } else {
            m0 = *(const short8*)(pc_en + off);
            m1 = *(const short8*)(pc_st + off);
        }
    };
    auto emit = [&](int bi, int c, f32x4 l0, f32x4 l1, short8 m0, short8 m1) {
        f32x4 v0, v1;
        if (c < 32) { v0 = l0; v1 = l1; }
        else {
            f32x4 e0, e1, s0, s1;
            bf16x8_f32(m0, e0, e1);
            bf16x8_f32(m1, s0, s1);
            v0 = e0 - s0; v1 = e1 - s1;
        }
        float* orow = spanout + sp_r * (3 * E_) + c * 64 + q * 8;
        __builtin_nontemporal_store(v0, (f32x4*)orow);
        __builtin_nontemporal_store(v1, (f32x4*)(orow + 4));
        *(short8*)(smem + bi * 8192 + r * 128 + ((q ^ (r & 7)) * 16)) = pack8v(v0, v1);
    };
    auto stageB = [&](int bi, int c) {
        char* dst = smem + 16384 + bi * 20480;
#pragma unroll
        for (int j = 0; j < 3; ++j) {
            const int idx = w * 3 + j;
            if (idx < 20) {
                const int nrow = idx * 8 + (lane >> 3);
                const int slot = (lane & 7) ^ (nrow & 7);
                gload16(Wt1 + (long long)nrow * GI_ + c * 64 + slot * 8,
                        dst + idx * 1024);
            }
        }
    };

    f32x4 acc[5];
#pragma unroll
    for (int nt = 0; nt < 5; ++nt) acc[nt] = (f32x4){0.f, 0.f, 0.f, 0.f};

    f32x4 pA0, pA1;  short8 mA0, mA1;   // ping
    f32x4 pB0, pB1;  short8 mB0, mB1;   // pong

    stageB(0, 0);
    asm volatile("" ::: "memory");
    ldreg(0, pA0, pA1, mA0, mA1);
    emit(0, 0, pA0, pA1, mA0, mA1);
    ldreg(1, pB0, pB1, mB0, mB1);

    auto phase = [&](int c, f32x4& u0, f32x4& u1, short8& um0, short8& um1,
                     f32x4& f0, f32x4& f1, short8& fm0, short8& fm1) {
        asm volatile("s_waitcnt vmcnt(4) lgkmcnt(0)" ::: "memory");
        __builtin_amdgcn_s_barrier();
        const int bi = c & 1;
        if (c + 1 < 48) {
            stageB(bi ^ 1, c + 1);
            asm volatile("" ::: "memory");   // DMAs issue before stores/loads
            emit(bi ^ 1, c + 1, u0, u1, um0, um1);
        }
        if (c + 2 < 48) ldreg(c + 2, f0, f1, fm0, fm1);
        const char* sAc = smem + bi * 8192;
        const char* sBc = smem + 16384 + bi * 20480;
#pragma unroll
        for (int ks = 0; ks < 2; ++ks) {
            short8 bfr[5];
#pragma unroll
            for (int nt = 0; nt < 5; ++nt) {
                const int nrow = cg * 80 + nt * 16 + lr;
                const int slot = (ks * 4 + hi) ^ (nrow & 7);
                bfr[nt] = *(const short8*)(sBc + nrow * 128 + slot * 16);
            }
            const int r2 = rg * 16 + lr;
            const int sl = (ks * 4 + hi) ^ (r2 & 7);
            short8 afr = *(const short8*)(sAc + r2 * 128 + sl * 16);
#pragma unroll
            for (int nt = 0; nt < 5; ++nt)
                acc[nt] = __builtin_amdgcn_mfma_f32_16x16x32_bf16(
                    afr, bfr[nt], acc[nt], 0, 0, 0);
        }
    };

    for (int cc = 0; cc < 48; cc += 2) {
        phase(cc,     pB0, pB1, mB0, mB1, pA0, pA1, mA0, mA1);
        phase(cc + 1, pA0, pA1, mA0, mA1, pB0, pB1, mB0, mB1);
    }
    asm volatile("s_waitcnt lgkmcnt(0)" ::: "memory");
    __builtin_amdgcn_s_barrier();

    __hip_bfloat16* hl = (__hip_bfloat16*)smem;

#pragma unroll
    for (int nt = 0; nt < 5; ++nt) {
        const int ch = cg * 80 + nt * 16 + lr;
        const float bb = (ch < HID_) ? b1[ch] : 0.f;
#pragma unroll
        for (int r4 = 0; r4 < 4; ++r4) {
            const int row = rg * 16 + hi * 4 + r4;
            float h = acc[nt][r4] + bb;
            hl[row * LSTR + ch] = __float2bfloat16(h > 0.f ? h : 0.f);
        }
    }
    __syncthreads();

    f32x4 acc2[5];
#pragma unroll
    for (int nt = 0; nt < 5; ++nt) acc2[nt] = (f32x4){0.f, 0.f, 0.f, 0.f};

#pragma unroll
    for (int ks = 0; ks < 5; ++ks) {
        const int k0 = ks * 32 + hi * 8;
        short8 bfr[5];
#pragma unroll
        for (int nt = 0; nt < 5; ++nt)
            bfr[nt] = *(const short8*)(Wt2 + (cg * 80 + nt * 16 + lr) * NPAD + k0);
        short8 afr = *(const short8*)&hl[(rg * 16 + lr) * LSTR + k0];
#pragma unroll
        for (int nt = 0; nt < 5; ++nt)
            acc2[nt] = __builtin_amdgcn_mfma_f32_16x16x32_bf16(
                afr, bfr[nt], acc2[nt], 0, 0, 0);
    }
    __syncthreads();

#pragma unroll
    for (int nt = 0; nt < 5; ++nt) {
        const int ch = cg * 80 + nt * 16 + lr;
        const float bb = (ch < HID_) ? b2[ch] : 0.f;
#pragma unroll
        for (int r4 = 0; r4 < 4; ++r4) {
            const int row = rg * 16 + hi * 4 + r4;
            float h = acc2[nt][r4] + bb;
            hl[row * LSTR + ch] = __float2bfloat16(h > 0.f ? h : 0.f);
        }
    }
    __syncthreads();

    {
        const int row = tid >> 3, oct = tid & 7;
        const int kb = oct * 19;
        const int ke = (kb + 19 > HID_) ? HID_ : kb + 19;
        float s = 0.f;
        for (int k = kb; k < ke; ++k)
            s += __bfloat162float(hl[row * LSTR + k]) * W3[k];
        s += __shfl_xor(s, 1);
        s += __shfl_xor(s, 2);
        s += __shfl_xor(s, 4);
        if (oct == 0) scoreout[span0 + row] = s + b3[0];
    }
}

extern "C" void kernel_launch(void* const* d_in, const int* in_sizes, int n_in,
                              void* d_out, int out_size, void* d_ws, size_t ws_size,
                              hipStream_t stream) {
    const float* x       = (const float*)d_in[0];
    const int*   starts  = (const int*)d_in[1];
    const int*   lengths = (const int*)d_in[2];
    const int*   nspans  = (const int*)d_in[3];
    const float* Wa1 = (const float*)d_in[4];
    const float* ba1 = (const float*)d_in[5];
    const float* Wa2 = (const float*)d_in[6];
    const float* ba2 = (const float*)d_in[7];
    const float* Wa3 = (const float*)d_in[8];
    const float* ba3 = (const float*)d_in[9];
    const float* Ws1 = (const float*)d_in[10];
    const float* bs1 = (const float*)d_in[11];
    const float* Ws2 = (const float*)d_in[12];
    const float* bs2 = (const float*)d_in[13];
    const float* Ws3 = (const float*)d_in[14];
    const float* bs3 = (const float*)d_in[15];

    float* out        = (float*)d_out;                       // span_emb [B,S,3E]
    float* out_scores = out + (long long)B_ * S_ * 3 * E_;   // scores [B,S]

    char* ws = (char*)d_ws;
    float*          attn    = (float*)ws;                       // 131072 B
    __hip_bfloat16* Wt1a    = (__hip_bfloat16*)(ws + 131072);
    __hip_bfloat16* Wt2a    = (__hip_bfloat16*)(ws + 458752);
    __hip_bfloat16* Wt1s    = (__hip_bfloat16*)(ws + 509952);
    __hip_bfloat16* Wt2s    = (__hip_bfloat16*)(ws + 1492992);
    float*          zerobuf = (float*)(ws + 1544192);           // 4 KB zeros
    float*          Ptile   = (float*)(ws + 2097152);           // 2 MB
    __hip_bfloat16* csum    = (__hip_bfloat16*)(ws + 4194304);  // 67 MB bf16

    transpose_all<<<2765, 256, 0, stream>>>(Wa1, Wa2, Ws1, Ws2,
                                            Wt1a, Wt2a, Wt1s, Wt2s, zerobuf);

    mlp_mfma<E_><<<(B_ * T_) / MROWS, 256, 0, stream>>>
        (x, Wt1a, ba1, Wt2a, ba2, Wa3, ba3, attn);

    wsum_tiles<<<B_ * 32, 256, 0, stream>>>(x, attn, Ptile);
    wcumsum   <<<B_ * 32, 256, 0, stream>>>(x, attn, Ptile, csum);

    span_score<<<500, 512, 0, stream>>>
        (x, csum, zerobuf, starts, lengths, nspans,
         Wt1s, bs1, Wt2s, bs2, Ws3, bs3, out, out_scores);
}